// Round 12
// baseline (273.993 us; speedup 1.0000x reference)
//
#include <hip/hip_runtime.h>
#include <hip/hip_bf16.h>

typedef short bf16x8 __attribute__((ext_vector_type(8)));
typedef float f32x4 __attribute__((ext_vector_type(4)));
typedef float f32x16 __attribute__((ext_vector_type(16)));
typedef unsigned short u16;
typedef u16 u16x8 __attribute__((ext_vector_type(8)));
typedef unsigned int u32;
typedef u32 u32x4 __attribute__((ext_vector_type(4)));

constexpr int NB = 8, NT = 2048, NC = 1024, NH = 64;
constexpr float L2E = 1.4426950408889634f;
constexpr float MBIAS = -23.083120654223414f;   // -16*log2(e): fixed softmax max
constexpr int NREP = 4;                          // diagnostic repeat (idempotent)

__device__ __forceinline__ u16 f2bf(float f) {
  __hip_bfloat16 h = __float2bfloat16(f);
  return __builtin_bit_cast(u16, h);
}
__device__ __forceinline__ bf16x8 ldsv8(const u16* p) {
  return __builtin_bit_cast(bf16x8, *(const u16x8*)p);
}
__device__ __forceinline__ u32 pk2(float a, float b) {
  return (u32)f2bf(a) | ((u32)f2bf(b) << 16);
}
__device__ __forceinline__ void glds16(const void* g, void* l) {
  __builtin_amdgcn_global_load_lds((const __attribute__((address_space(1))) void*)g,
                                   (__attribute__((address_space(3))) void*)l, 16, 0, 0);
}

// ---------------- kernel 0: W fp32 [C][H] -> bf16 W^T [3][H][C]; Wq scaled 0.125
__global__ __launch_bounds__(256) void wconv(const float* __restrict__ wk,
                                             const float* __restrict__ wq,
                                             const float* __restrict__ wv,
                                             u16* __restrict__ wb) {
  int idx = blockIdx.x * 256 + threadIdx.x;   // 3*64*1024
  int m = idx >> 16, rem = idx & 65535;
  int n = rem >> 10, kk = rem & 1023;
  const float* s = (m == 0) ? wq : ((m == 1) ? wk : wv);
  float f = s[kk * NH + n];
  if (m == 0) f *= 0.125f;
  wb[idx] = f2bf(f);
}

// ---------------- kernel 1: fused QKV projection (x4 diagnostic repeat)
__global__ __launch_bounds__(512, 4) void qkv_proj(const float* __restrict__ x,
                                                   const u16* __restrict__ wb,
                                                   u16* __restrict__ qg,
                                                   u16* __restrict__ kg,
                                                   u16* __restrict__ vtg) {
  __shared__ __align__(16) float xbuf[2][32 * 64];   // 8 KB each (fp32 x tile)
  __shared__ __align__(16) u16 wlds[2][192 * 64];    // 24 KB each (bf16 W tile)
  __shared__ __align__(16) u16 vt[64][40];           // V^T epilogue staging
  const int tid = threadIdx.x, w = tid >> 6, l = tid & 63;
  const int lr = l & 15, lg = l >> 4;
  const int wr = w & 1, wc = w >> 1;                 // row-half, col-group
  const int row0 = blockIdx.x * 32;

#define GSTAGE(buf, kb)                                                       \
  {                                                                           \
    int row = w * 4 + (l >> 4);                                               \
    int srci = ((l & 15) * 16) ^ ((row & 7) << 4);                            \
    glds16((const char*)x + (size_t)(row0 + row) * 4096 + (kb) * 256 + srci,  \
           (char*)&xbuf[buf][0] + w * 1024);                                  \
    _Pragma("unroll")                                                         \
    for (int i = 0; i < 3; ++i) {                                             \
      int seg = w * 3 + i;                                                    \
      int wrow = seg * 8 + (l >> 3);                                          \
      int wsrc = ((l & 7) * 16) ^ ((wrow & 7) << 4);                          \
      glds16((const char*)wb + (size_t)wrow * 2048 + (kb) * 128 + wsrc,       \
             (char*)&wlds[buf][0] + seg * 1024);                              \
    }                                                                         \
  }

#pragma unroll 1
  for (int rep = 0; rep < NREP; ++rep) {
    asm volatile("" ::: "memory");     // block cross-rep CSE/hoisting

    f32x4 acc[3];
#pragma unroll
    for (int nt = 0; nt < 3; ++nt) acc[nt] = (f32x4){0.f, 0.f, 0.f, 0.f};

    GSTAGE(0, 0);
    __syncthreads();

#pragma unroll
    for (int kb = 0; kb < 16; ++kb) {
      const int cur = kb & 1;
      if (kb < 15) GSTAGE(cur ^ 1, kb + 1);
      bf16x8 af[2];
#pragma unroll
      for (int ks = 0; ks < 2; ++ks) {
        int rowl = wr * 16 + lr;
        int sz = (lr & 7) << 4;
        int c0 = ks * 128 + lg * 32;
        f32x4 v0 = *(const f32x4*)((const char*)&xbuf[cur][0] + rowl * 256 + (c0 ^ sz));
        f32x4 v1 = *(const f32x4*)((const char*)&xbuf[cur][0] + rowl * 256 + ((c0 + 16) ^ sz));
        u16x8 tt;
#pragma unroll
        for (int j = 0; j < 4; ++j) {
          tt[j]     = f2bf(v0[j]);
          tt[j + 4] = f2bf(v1[j]);
        }
        af[ks] = __builtin_bit_cast(bf16x8, tt);
      }
#pragma unroll
      for (int nt = 0; nt < 3; ++nt)
#pragma unroll
        for (int ks = 0; ks < 2; ++ks) {
          int wrow = wc * 48 + nt * 16 + lr;
          int cb = (ks * 64 + lg * 16) ^ ((lr & 7) << 4);
          bf16x8 bf_ = ldsv8((const u16*)((const char*)&wlds[cur][0] + wrow * 128 + cb));
          acc[nt] = __builtin_amdgcn_mfma_f32_16x16x32_bf16(af[ks], bf_, acc[nt], 0, 0, 0);
        }
      __syncthreads();
    }

    // epilogue: D row = wr*16 + lg*4 + r, col = wc*48 + nt*16 + lr
#pragma unroll
    for (int nt = 0; nt < 3; ++nt)
#pragma unroll
      for (int r = 0; r < 4; ++r) {
        int g = wc * 48 + nt * 16 + lr;
        int rl = wr * 16 + lg * 4 + r;
        u16 bv = f2bf(acc[nt][r]);
        if (g < 64)       qg[(size_t)(row0 + rl) * NH + g] = bv;
        else if (g < 128) kg[(size_t)(row0 + rl) * NH + (g - 64)] = bv;
        else              vt[g - 128][rl] = bv;
      }
    __syncthreads();
    if (tid < 256) {                     // 256 vec8 stores = 64 h x 32 t exactly
      int b = row0 >> 11, t0 = row0 & 2047;
      int h = tid >> 2, tc = (tid & 3) * 8;
      u16x8 vv = *(const u16x8*)&vt[h][tc];
      *(u16x8*)(vtg + ((size_t)b * NH + h) * NT + t0 + tc) = vv;
    }
    __syncthreads();                     // protect vt/xbuf/wlds across reps
  }
#undef GSTAGE
}

// ---------------- kernel 2a: flash phase A (x4 diagnostic repeat)
__global__ __launch_bounds__(256, 4) void flashA(const u16* __restrict__ qg,
                                                 const u16* __restrict__ kg,
                                                 const u16* __restrict__ vtg,
                                                 float* __restrict__ part) {
  __shared__ float om[4][32][68];
  const int tid = threadIdx.x, w = tid >> 6, l = tid & 63;
  const int l31 = l & 31, hb = l >> 5;
  const int b = blockIdx.x & 7;
  int bl = blockIdx.x >> 3;              // 0..287 per batch
  int g = 0, off = 0;
  while (bl >= off + 8 * (g + 1)) { off += 8 * (g + 1); ++g; }
  int qq = bl - off;
  int tdiv = qq / (g + 1);
  const int t = 8 * g + tdiv;            // q-tile 0..63
  const int ch = qq - (g + 1) * tdiv;    // kv chunk 0..g
  const int kvb = ch * 256 + w * 64;
  const bool valid = kvb <= t * 32 + 31;
  const int qrow = t * 32 + l31;

#pragma unroll 1
  for (int rep = 0; rep < NREP; ++rep) {
    asm volatile("" ::: "memory");     // block cross-rep CSE/hoisting

    f32x16 o0, o1;
#pragma unroll
    for (int r = 0; r < 16; ++r) { o0[r] = 0.f; o1[r] = 0.f; }
    float lsum = 0.f;

    if (valid) {
      // ---- batched Q, K, V loads: 20 VMEM ops up front ----
      bf16x8 qf[4];
      const u16* qp = qg + ((size_t)b * NT + qrow) * NH;
#pragma unroll
      for (int ks = 0; ks < 4; ++ks) qf[ks] = ldsv8(qp + ks * 16 + hb * 8);
      bf16x8 kf[4][2];
      const u16* kp = kg + ((size_t)b * NT + kvb) * NH;
#pragma unroll
      for (int ks = 0; ks < 4; ++ks) {
        kf[ks][0] = ldsv8(kp + (size_t)l31 * NH + ks * 16 + hb * 8);
        kf[ks][1] = ldsv8(kp + (size_t)(32 + l31) * NH + ks * 16 + hb * 8);
      }
      bf16x8 vf[2][2][2];
      const u16* vp = vtg + (size_t)b * NH * NT + kvb;
#pragma unroll
      for (int ht = 0; ht < 2; ++ht)
#pragma unroll
        for (int kvt = 0; kvt < 2; ++kvt)
#pragma unroll
          for (int ks2 = 0; ks2 < 2; ++ks2)
            vf[ht][kvt][ks2] = ldsv8(vp + (size_t)(ht * 32 + l31) * NT +
                                     kvt * 32 + ks2 * 16 + hb * 8);
      __builtin_amdgcn_sched_barrier(0);

      const bool diag = (kvb + 63 > t * 32);
#pragma unroll
      for (int kvt = 0; kvt < 2; ++kvt) {
        f32x16 s;
#pragma unroll
        for (int r = 0; r < 16; ++r) s[r] = 0.f;
        __builtin_amdgcn_s_setprio(1);
#pragma unroll
        for (int ks = 0; ks < 4; ++ks)
          s = __builtin_amdgcn_mfma_f32_32x32x16_bf16(kf[ks][kvt], qf[ks], s, 0, 0, 0);
        __builtin_amdgcn_s_setprio(0);
        if (diag) {
#pragma unroll
          for (int r = 0; r < 16; ++r) {
            int kv0 = kvb + kvt * 32 + (r & 3) + 8 * (r >> 2) + 4 * hb;
            if (kv0 > qrow) s[r] = -1e30f;
          }
        }
        float p[16];
#pragma unroll
        for (int r = 0; r < 16; ++r) {
          p[r] = exp2f(fmaf(s[r], L2E, MBIAS));
          lsum += p[r];
        }
        u32 pf[2][4];
#pragma unroll
        for (int ks2 = 0; ks2 < 2; ++ks2) {
          u32 a0 = pk2(p[8 * ks2 + 0], p[8 * ks2 + 1]);
          u32 a1 = pk2(p[8 * ks2 + 2], p[8 * ks2 + 3]);
          u32 b0 = pk2(p[8 * ks2 + 4], p[8 * ks2 + 5]);
          u32 b1 = pk2(p[8 * ks2 + 6], p[8 * ks2 + 7]);
          u32 e0 = hb ? a0 : b0, e1 = hb ? a1 : b1;
          e0 = __shfl_xor(e0, 32);
          e1 = __shfl_xor(e1, 32);
          pf[ks2][0] = hb ? e0 : a0;
          pf[ks2][1] = hb ? e1 : a1;
          pf[ks2][2] = hb ? b0 : e0;
          pf[ks2][3] = hb ? b1 : e1;
        }
        __builtin_amdgcn_s_setprio(1);
#pragma unroll
        for (int ht = 0; ht < 2; ++ht)
#pragma unroll
          for (int ks2 = 0; ks2 < 2; ++ks2) {
            u32x4 pw = {pf[ks2][0], pf[ks2][1], pf[ks2][2], pf[ks2][3]};
            bf16x8 pv = __builtin_bit_cast(bf16x8, pw);
            if (ht == 0) o0 = __builtin_amdgcn_mfma_f32_32x32x16_bf16(vf[0][kvt][ks2], pv, o0, 0, 0, 0);
            else         o1 = __builtin_amdgcn_mfma_f32_32x32x16_bf16(vf[1][kvt][ks2], pv, o1, 0, 0, 0);
          }
        __builtin_amdgcn_s_setprio(0);
      }
    }
    lsum += __shfl_xor(lsum, 32);

    // ---- each wave writes its own LDS slice (zeros if invalid), 1 barrier ----
    {
      float* dst = &om[w][l31][0];
#pragma unroll
      for (int ht = 0; ht < 2; ++ht)
#pragma unroll
        for (int rq = 0; rq < 4; ++rq) {
          f32x4 q4;
#pragma unroll
          for (int c = 0; c < 4; ++c) q4[c] = ht ? o1[4 * rq + c] : o0[4 * rq + c];
          *(f32x4*)&dst[ht * 32 + rq * 8 + hb * 4] = q4;
        }
      if (hb == 0) dst[64] = lsum;
    }
    __syncthreads();
    // ---- cooperative sum of 4 wave slices -> part [32][68] ----
    {
      int row = tid >> 3, c8 = (tid & 7) * 8;
      f32x4 a0 = {0.f, 0.f, 0.f, 0.f}, a1 = {0.f, 0.f, 0.f, 0.f};
      float ls = 0.f;
#pragma unroll
      for (int ww = 0; ww < 4; ++ww) {
        a0 += *(const f32x4*)&om[ww][row][c8];
        a1 += *(const f32x4*)&om[ww][row][c8 + 4];
        ls += om[ww][row][64];
      }
      float* pp = part + (((size_t)(b * 64 + t) * 8) + ch) * 2176 + row * 68;
      *(f32x4*)(pp + c8)     = a0;
      *(f32x4*)(pp + c8 + 4) = a1;
      if ((tid & 7) == 0) pp[64] = ls;
    }
    __syncthreads();                     // protect om across reps
  }
}

// ---------------- kernel 2b: flash phase B — sum chunk partials + normalize
__global__ __launch_bounds__(256) void flashB(const float* __restrict__ part,
                                              float* __restrict__ out) {
  const int tid = threadIdx.x;
  const int b = blockIdx.x & 7, t = blockIdx.x >> 3;
  const int nch = (t >> 3) + 1;
  const int row = tid >> 3, c8 = (tid & 7) * 8;
  const float* p0 = part + ((size_t)(b * 64 + t) * 8) * 2176 + row * 68;
  f32x4 a0 = {0.f, 0.f, 0.f, 0.f}, a1 = {0.f, 0.f, 0.f, 0.f};
  float ls = 0.f;
  for (int ch = 0; ch < nch; ++ch) {
    const float* pp = p0 + ch * 2176;
    a0 += *(const f32x4*)(pp + c8);
    a1 += *(const f32x4*)(pp + c8 + 4);
    ls += pp[64];
  }
  float rl = 1.f / ls;
  size_t ob = ((size_t)b * NT + t * 32 + row) * NH + c8;
  *(f32x4*)&out[ob]     = a0 * rl;
  *(f32x4*)&out[ob + 4] = a1 * rl;
}

extern "C" void kernel_launch(void* const* d_in, const int* in_sizes, int n_in,
                              void* d_out, int out_size, void* d_ws, size_t ws_size,
                              hipStream_t stream) {
  const float* x  = (const float*)d_in[0];
  const float* wk = (const float*)d_in[1];
  const float* wq = (const float*)d_in[2];
  const float* wv = (const float*)d_in[3];
  float* out = (float*)d_out;

  u16* qg  = (u16*)d_ws;                 // [B*T][64] bf16
  u16* kg  = qg + NB * NT * NH;          // [B*T][64] bf16
  u16* vtg = kg + NB * NT * NH;          // [B][64][T] bf16
  u16* wb  = vtg + NB * NT * NH;         // [3][64][1024] bf16
  float* part = (float*)(wb + 3 * NH * NC);  // [B*64 qtiles][8 chunks][32][68] f32

  wconv<<<768, 256, 0, stream>>>(wk, wq, wv, wb);
  qkv_proj<<<512, 512, 0, stream>>>(x, wb, qg, kg, vtg);
  flashA<<<2304, 256, 0, stream>>>(qg, kg, vtg, part);
  flashB<<<512, 256, 0, stream>>>(part, out);
}

// Round 13
// 78.215 us; speedup vs baseline: 3.5031x; 3.5031x over previous
//
#include <hip/hip_runtime.h>
#include <hip/hip_bf16.h>

typedef short bf16x8 __attribute__((ext_vector_type(8)));
typedef float f32x4 __attribute__((ext_vector_type(4)));
typedef float f32x16 __attribute__((ext_vector_type(16)));
typedef unsigned short u16;
typedef u16 u16x8 __attribute__((ext_vector_type(8)));
typedef unsigned int u32;
typedef u32 u32x4 __attribute__((ext_vector_type(4)));

constexpr int NB = 8, NT = 2048, NC = 1024, NH = 64;
constexpr float L2E = 1.4426950408889634f;
constexpr float MBIAS = -23.083120654223414f;   // -16*log2(e): fixed softmax max

__device__ __forceinline__ u16 f2bf(float f) {
  __hip_bfloat16 h = __float2bfloat16(f);
  return __builtin_bit_cast(u16, h);
}
__device__ __forceinline__ bf16x8 ldsv8(const u16* p) {
  return __builtin_bit_cast(bf16x8, *(const u16x8*)p);
}
__device__ __forceinline__ u32 pk2(float a, float b) {
  return (u32)f2bf(a) | ((u32)f2bf(b) << 16);
}
__device__ __forceinline__ void glds16(const void* g, void* l) {
  __builtin_amdgcn_global_load_lds((const __attribute__((address_space(1))) void*)g,
                                   (__attribute__((address_space(3))) void*)l, 16, 0, 0);
}

// ---------------- kernel 0: W fp32 [C][H] -> bf16 W^T [3][H][C]; Wq scaled 0.125
__global__ __launch_bounds__(256) void wconv(const float* __restrict__ wk,
                                             const float* __restrict__ wq,
                                             const float* __restrict__ wv,
                                             u16* __restrict__ wb) {
  int idx = blockIdx.x * 256 + threadIdx.x;   // 3*64*1024
  int m = idx >> 16, rem = idx & 65535;
  int n = rem >> 10, kk = rem & 1023;
  const float* s = (m == 0) ? wq : ((m == 1) ? wk : wv);
  float f = s[kk * NH + n];
  if (m == 0) f *= 0.125f;
  wb[idx] = f2bf(f);
}

// ---------------- kernel 1: fused QKV projection — 8 waves/block, 16 waves/CU.
// Coalesced epilogue: q,k,v all routed through LDS -> vec8 stores.
__global__ __launch_bounds__(512, 4) void qkv_proj(const float* __restrict__ x,
                                                   const u16* __restrict__ wb,
                                                   u16* __restrict__ qg,
                                                   u16* __restrict__ kg,
                                                   u16* __restrict__ vtg) {
  __shared__ __align__(16) float xbuf[2][32 * 64];   // 8 KB each (fp32 x tile)
  __shared__ __align__(16) u16 wlds[2][192 * 64];    // 24 KB each (bf16 W tile)
  __shared__ __align__(16) u16 vt[64][40];           // V^T epilogue staging
  __shared__ __align__(16) u16 qs[32][72];           // Q epilogue staging
  __shared__ __align__(16) u16 ks_[32][72];          // K epilogue staging
  const int tid = threadIdx.x, w = tid >> 6, l = tid & 63;
  const int lr = l & 15, lg = l >> 4;
  const int wr = w & 1, wc = w >> 1;                 // row-half, col-group
  const int row0 = blockIdx.x * 32;

  f32x4 acc[3];
#pragma unroll
  for (int nt = 0; nt < 3; ++nt) acc[nt] = (f32x4){0.f, 0.f, 0.f, 0.f};

  // stage x (8KB: 1 glds/wave) + W (24KB: 3 glds/wave) for k-block kb.
  // content[row][c] = src[row][c ^ ((row&7)<<4)]; W LDS seg = 1024 B.
#define GSTAGE(buf, kb)                                                       \
  {                                                                           \
    int row = w * 4 + (l >> 4);                                               \
    int srci = ((l & 15) * 16) ^ ((row & 7) << 4);                            \
    glds16((const char*)x + (size_t)(row0 + row) * 4096 + (kb) * 256 + srci,  \
           (char*)&xbuf[buf][0] + w * 1024);                                  \
    _Pragma("unroll")                                                         \
    for (int i = 0; i < 3; ++i) {                                             \
      int seg = w * 3 + i;                                                    \
      int wrow = seg * 8 + (l >> 3);                                          \
      int wsrc = ((l & 7) * 16) ^ ((wrow & 7) << 4);                          \
      glds16((const char*)wb + (size_t)wrow * 2048 + (kb) * 128 + wsrc,       \
             (char*)&wlds[buf][0] + seg * 1024);                              \
    }                                                                         \
  }

  GSTAGE(0, 0);
  __syncthreads();

#pragma unroll
  for (int kb = 0; kb < 16; ++kb) {
    const int cur = kb & 1;
    if (kb < 15) GSTAGE(cur ^ 1, kb + 1);
    bf16x8 af[2];
#pragma unroll
    for (int ks = 0; ks < 2; ++ks) {
      int rowl = wr * 16 + lr;
      int sz = (lr & 7) << 4;
      int c0 = ks * 128 + lg * 32;
      f32x4 v0 = *(const f32x4*)((const char*)&xbuf[cur][0] + rowl * 256 + (c0 ^ sz));
      f32x4 v1 = *(const f32x4*)((const char*)&xbuf[cur][0] + rowl * 256 + ((c0 + 16) ^ sz));
      u16x8 tt;
#pragma unroll
      for (int j = 0; j < 4; ++j) {
        tt[j]     = f2bf(v0[j]);
        tt[j + 4] = f2bf(v1[j]);
      }
      af[ks] = __builtin_bit_cast(bf16x8, tt);
    }
#pragma unroll
    for (int nt = 0; nt < 3; ++nt)
#pragma unroll
      for (int ks = 0; ks < 2; ++ks) {
        int wrow = wc * 48 + nt * 16 + lr;
        int cb = (ks * 64 + lg * 16) ^ ((lr & 7) << 4);
        bf16x8 bf_ = ldsv8((const u16*)((const char*)&wlds[cur][0] + wrow * 128 + cb));
        acc[nt] = __builtin_amdgcn_mfma_f32_16x16x32_bf16(af[ks], bf_, acc[nt], 0, 0, 0);
      }
    __syncthreads();
  }
#undef GSTAGE

  // epilogue: stage q,k,v in LDS, then coalesced vec8 stores
#pragma unroll
  for (int nt = 0; nt < 3; ++nt)
#pragma unroll
    for (int r = 0; r < 4; ++r) {
      int g = wc * 48 + nt * 16 + lr;
      int rl = wr * 16 + lg * 4 + r;
      u16 bv = f2bf(acc[nt][r]);
      if (g < 64)       qs[rl][g] = bv;
      else if (g < 128) ks_[rl][g - 64] = bv;
      else              vt[g - 128][rl] = bv;
    }
  __syncthreads();
  if (tid < 256) {
    int b = row0 >> 11, t0 = row0 & 2047;
    {
      int row = tid >> 3, c8 = (tid & 7) * 8;     // 32 rows x 64 cols
      *(u16x8*)(qg + (size_t)(row0 + row) * NH + c8) = *(const u16x8*)&qs[row][c8];
      *(u16x8*)(kg + (size_t)(row0 + row) * NH + c8) = *(const u16x8*)&ks_[row][c8];
    }
    {
      int h = tid >> 2, tc = (tid & 3) * 8;       // 64 h x 32 t
      u16x8 vv = *(const u16x8*)&vt[h][tc];
      *(u16x8*)(vtg + ((size_t)b * NH + h) * NT + t0 + tc) = vv;
    }
  }
}

// ---------------- kernel 2: causal flash — single kernel, per-wave kv loop.
// 512 blocks = 8 b x 64 q32-tiles (heavy/light interleaved); 4 waves by
// kv-parity, each looping kt += 4. Const-max softmax => in-register adds
// across iterations; one LDS merge; direct out write. No part, no flashB.
__global__ __launch_bounds__(256, 4) void flash(const u16* __restrict__ qg,
                                                const u16* __restrict__ kg,
                                                const u16* __restrict__ vtg,
                                                float* __restrict__ out) {
  __shared__ float om[4][32][68];
  const int tid = threadIdx.x, w = tid >> 6, l = tid & 63;
  const int l31 = l & 31, hb = l >> 5;
  const int u = blockIdx.x;
  const int b = u & 7;                             // batch == XCD
  const int g = u >> 3;                            // 0..63
  const int t = (g & 1) ? (63 - (g >> 1)) : (g >> 1);  // heavy/light pairing
  const int nkt = (t + 2) >> 1;                    // kv64 tiles for this q-tile
  const int qrow = t * 32 + l31;

  bf16x8 qf[4];
  {
    const u16* qp = qg + ((size_t)b * NT + qrow) * NH;
#pragma unroll
    for (int ks = 0; ks < 4; ++ks) qf[ks] = ldsv8(qp + ks * 16 + hb * 8);
  }
  f32x16 o0, o1;
#pragma unroll
  for (int r = 0; r < 16; ++r) { o0[r] = 0.f; o1[r] = 0.f; }
  float lsum = 0.f;
  const u16* kbp = kg + (size_t)b * NT * NH;
  const u16* vbp = vtg + (size_t)b * NH * NT;

#pragma unroll 1
  for (int kt = w; kt < nkt; kt += 4) {
    const int kvb = kt * 64;
    // ---- batched K,V loads (16 VMEM ops), pinned before compute ----
    bf16x8 kf[4][2];
    const u16* kp = kbp + (size_t)kvb * NH;
#pragma unroll
    for (int ks = 0; ks < 4; ++ks) {
      kf[ks][0] = ldsv8(kp + (size_t)l31 * NH + ks * 16 + hb * 8);
      kf[ks][1] = ldsv8(kp + (size_t)(32 + l31) * NH + ks * 16 + hb * 8);
    }
    bf16x8 vf[2][2][2];
    const u16* vp = vbp + kvb;
#pragma unroll
    for (int ht = 0; ht < 2; ++ht)
#pragma unroll
      for (int kvt = 0; kvt < 2; ++kvt)
#pragma unroll
        for (int ks2 = 0; ks2 < 2; ++ks2)
          vf[ht][kvt][ks2] = ldsv8(vp + (size_t)(ht * 32 + l31) * NT +
                                   kvt * 32 + ks2 * 16 + hb * 8);
    __builtin_amdgcn_sched_barrier(0);

    const bool diag = (kvb + 63 > t * 32);
#pragma unroll
    for (int kvt = 0; kvt < 2; ++kvt) {
      f32x16 s;
#pragma unroll
      for (int r = 0; r < 16; ++r) s[r] = 0.f;
      __builtin_amdgcn_s_setprio(1);
#pragma unroll
      for (int ks = 0; ks < 4; ++ks)
        s = __builtin_amdgcn_mfma_f32_32x32x16_bf16(kf[ks][kvt], qf[ks], s, 0, 0, 0);
      __builtin_amdgcn_s_setprio(0);
      if (diag) {
#pragma unroll
        for (int r = 0; r < 16; ++r) {
          int kv0 = kvb + kvt * 32 + (r & 3) + 8 * (r >> 2) + 4 * hb;
          if (kv0 > qrow) s[r] = -1e30f;
        }
      }
      float p[16];
#pragma unroll
      for (int r = 0; r < 16; ++r) {
        p[r] = exp2f(fmaf(s[r], L2E, MBIAS));
        lsum += p[r];
      }
      u32 pf[2][4];
#pragma unroll
      for (int ks2 = 0; ks2 < 2; ++ks2) {
        u32 a0 = pk2(p[8 * ks2 + 0], p[8 * ks2 + 1]);
        u32 a1 = pk2(p[8 * ks2 + 2], p[8 * ks2 + 3]);
        u32 b0 = pk2(p[8 * ks2 + 4], p[8 * ks2 + 5]);
        u32 b1 = pk2(p[8 * ks2 + 6], p[8 * ks2 + 7]);
        u32 e0 = hb ? a0 : b0, e1 = hb ? a1 : b1;
        e0 = __shfl_xor(e0, 32);
        e1 = __shfl_xor(e1, 32);
        pf[ks2][0] = hb ? e0 : a0;
        pf[ks2][1] = hb ? e1 : a1;
        pf[ks2][2] = hb ? b0 : e0;
        pf[ks2][3] = hb ? b1 : e1;
      }
      __builtin_amdgcn_s_setprio(1);
#pragma unroll
      for (int ht = 0; ht < 2; ++ht)
#pragma unroll
        for (int ks2 = 0; ks2 < 2; ++ks2) {
          u32x4 pw = {pf[ks2][0], pf[ks2][1], pf[ks2][2], pf[ks2][3]};
          bf16x8 pv = __builtin_bit_cast(bf16x8, pw);
          if (ht == 0) o0 = __builtin_amdgcn_mfma_f32_32x32x16_bf16(vf[0][kvt][ks2], pv, o0, 0, 0, 0);
          else         o1 = __builtin_amdgcn_mfma_f32_32x32x16_bf16(vf[1][kvt][ks2], pv, o1, 0, 0, 0);
        }
      __builtin_amdgcn_s_setprio(0);
    }
  }
  lsum += __shfl_xor(lsum, 32);

  // ---- each wave writes its own LDS slice, 1 barrier, merge + store ----
  {
    float* dst = &om[w][l31][0];
#pragma unroll
    for (int ht = 0; ht < 2; ++ht)
#pragma unroll
      for (int rq = 0; rq < 4; ++rq) {
        f32x4 q4;
#pragma unroll
        for (int c = 0; c < 4; ++c) q4[c] = ht ? o1[4 * rq + c] : o0[4 * rq + c];
        *(f32x4*)&dst[ht * 32 + rq * 8 + hb * 4] = q4;
      }
    if (hb == 0) dst[64] = lsum;
  }
  __syncthreads();
  {
    int row = tid >> 3, c8 = (tid & 7) * 8;
    f32x4 a0 = {0.f, 0.f, 0.f, 0.f}, a1 = {0.f, 0.f, 0.f, 0.f};
    float ls = 0.f;
#pragma unroll
    for (int ww = 0; ww < 4; ++ww) {
      a0 += *(const f32x4*)&om[ww][row][c8];
      a1 += *(const f32x4*)&om[ww][row][c8 + 4];
      ls += om[ww][row][64];
    }
    float rl = 1.f / ls;
    size_t ob = ((size_t)b * NT + t * 32 + row) * NH + c8;
    *(f32x4*)&out[ob]     = a0 * rl;
    *(f32x4*)&out[ob + 4] = a1 * rl;
  }
}

extern "C" void kernel_launch(void* const* d_in, const int* in_sizes, int n_in,
                              void* d_out, int out_size, void* d_ws, size_t ws_size,
                              hipStream_t stream) {
  const float* x  = (const float*)d_in[0];
  const float* wk = (const float*)d_in[1];
  const float* wq = (const float*)d_in[2];
  const float* wv = (const float*)d_in[3];
  float* out = (float*)d_out;

  u16* qg  = (u16*)d_ws;                 // [B*T][64] bf16
  u16* kg  = qg + NB * NT * NH;          // [B*T][64] bf16
  u16* vtg = kg + NB * NT * NH;          // [B][64][T] bf16
  u16* wb  = vtg + NB * NT * NH;         // [3][64][1024] bf16

  wconv<<<768, 256, 0, stream>>>(wk, wq, wv, wb);
  qkv_proj<<<512, 512, 0, stream>>>(x, wb, qg, kg, vtg);
  flash<<<512, 256, 0, stream>>>(qg, kg, vtg, out);
}

// Round 14
// 52.096 us; speedup vs baseline: 5.2594x; 1.5014x over previous
//
#include <hip/hip_runtime.h>
#include <hip/hip_bf16.h>

typedef short bf16x8 __attribute__((ext_vector_type(8)));
typedef float f32x4 __attribute__((ext_vector_type(4)));
typedef float f32x16 __attribute__((ext_vector_type(16)));
typedef unsigned short u16;
typedef u16 u16x8 __attribute__((ext_vector_type(8)));
typedef unsigned int u32;
typedef u32 u32x4 __attribute__((ext_vector_type(4)));

constexpr int NB = 8, NT = 2048, NC = 1024, NH = 64;
constexpr float L2E = 1.4426950408889634f;
constexpr float MBIAS = -23.083120654223414f;   // -16*log2(e): fixed softmax max

__device__ __forceinline__ u16 f2bf(float f) {
  __hip_bfloat16 h = __float2bfloat16(f);
  return __builtin_bit_cast(u16, h);
}
__device__ __forceinline__ bf16x8 ldsv8(const u16* p) {
  return __builtin_bit_cast(bf16x8, *(const u16x8*)p);
}
__device__ __forceinline__ u32 pk2(float a, float b) {
  return (u32)f2bf(a) | ((u32)f2bf(b) << 16);
}
__device__ __forceinline__ void glds16(const void* g, void* l) {
  __builtin_amdgcn_global_load_lds((const __attribute__((address_space(1))) void*)g,
                                   (__attribute__((address_space(3))) void*)l, 16, 0, 0);
}

// ---------------- kernel 0: W fp32 [C][H] -> bf16 W^T [3][H][C]; Wq scaled 0.125
__global__ __launch_bounds__(256) void wconv(const float* __restrict__ wk,
                                             const float* __restrict__ wq,
                                             const float* __restrict__ wv,
                                             u16* __restrict__ wb) {
  int idx = blockIdx.x * 256 + threadIdx.x;   // 3*64*1024
  int m = idx >> 16, rem = idx & 65535;
  int n = rem >> 10, kk = rem & 1023;
  const float* s = (m == 0) ? wq : ((m == 1) ? wk : wv);
  float f = s[kk * NH + n];
  if (m == 0) f *= 0.125f;
  wb[idx] = f2bf(f);
}

// ---------------- kernel 1: fused QKV projection (r13, unchanged)
__global__ __launch_bounds__(512, 4) void qkv_proj(const float* __restrict__ x,
                                                   const u16* __restrict__ wb,
                                                   u16* __restrict__ qg,
                                                   u16* __restrict__ kg,
                                                   u16* __restrict__ vtg) {
  __shared__ __align__(16) float xbuf[2][32 * 64];
  __shared__ __align__(16) u16 wlds[2][192 * 64];
  __shared__ __align__(16) u16 vt[64][40];
  __shared__ __align__(16) u16 qs[32][72];
  __shared__ __align__(16) u16 ks_[32][72];
  const int tid = threadIdx.x, w = tid >> 6, l = tid & 63;
  const int lr = l & 15, lg = l >> 4;
  const int wr = w & 1, wc = w >> 1;
  const int row0 = blockIdx.x * 32;

  f32x4 acc[3];
#pragma unroll
  for (int nt = 0; nt < 3; ++nt) acc[nt] = (f32x4){0.f, 0.f, 0.f, 0.f};

#define GSTAGE(buf, kb)                                                       \
  {                                                                           \
    int row = w * 4 + (l >> 4);                                               \
    int srci = ((l & 15) * 16) ^ ((row & 7) << 4);                            \
    glds16((const char*)x + (size_t)(row0 + row) * 4096 + (kb) * 256 + srci,  \
           (char*)&xbuf[buf][0] + w * 1024);                                  \
    _Pragma("unroll")                                                         \
    for (int i = 0; i < 3; ++i) {                                             \
      int seg = w * 3 + i;                                                    \
      int wrow = seg * 8 + (l >> 3);                                          \
      int wsrc = ((l & 7) * 16) ^ ((wrow & 7) << 4);                          \
      glds16((const char*)wb + (size_t)wrow * 2048 + (kb) * 128 + wsrc,       \
             (char*)&wlds[buf][0] + seg * 1024);                              \
    }                                                                         \
  }

  GSTAGE(0, 0);
  __syncthreads();

#pragma unroll
  for (int kb = 0; kb < 16; ++kb) {
    const int cur = kb & 1;
    if (kb < 15) GSTAGE(cur ^ 1, kb + 1);
    bf16x8 af[2];
#pragma unroll
    for (int ks = 0; ks < 2; ++ks) {
      int rowl = wr * 16 + lr;
      int sz = (lr & 7) << 4;
      int c0 = ks * 128 + lg * 32;
      f32x4 v0 = *(const f32x4*)((const char*)&xbuf[cur][0] + rowl * 256 + (c0 ^ sz));
      f32x4 v1 = *(const f32x4*)((const char*)&xbuf[cur][0] + rowl * 256 + ((c0 + 16) ^ sz));
      u16x8 tt;
#pragma unroll
      for (int j = 0; j < 4; ++j) {
        tt[j]     = f2bf(v0[j]);
        tt[j + 4] = f2bf(v1[j]);
      }
      af[ks] = __builtin_bit_cast(bf16x8, tt);
    }
#pragma unroll
    for (int nt = 0; nt < 3; ++nt)
#pragma unroll
      for (int ks = 0; ks < 2; ++ks) {
        int wrow = wc * 48 + nt * 16 + lr;
        int cb = (ks * 64 + lg * 16) ^ ((lr & 7) << 4);
        bf16x8 bf_ = ldsv8((const u16*)((const char*)&wlds[cur][0] + wrow * 128 + cb));
        acc[nt] = __builtin_amdgcn_mfma_f32_16x16x32_bf16(af[ks], bf_, acc[nt], 0, 0, 0);
      }
    __syncthreads();
  }
#undef GSTAGE

#pragma unroll
  for (int nt = 0; nt < 3; ++nt)
#pragma unroll
    for (int r = 0; r < 4; ++r) {
      int g = wc * 48 + nt * 16 + lr;
      int rl = wr * 16 + lg * 4 + r;
      u16 bv = f2bf(acc[nt][r]);
      if (g < 64)       qs[rl][g] = bv;
      else if (g < 128) ks_[rl][g - 64] = bv;
      else              vt[g - 128][rl] = bv;
    }
  __syncthreads();
  if (tid < 256) {
    int b = row0 >> 11, t0 = row0 & 2047;
    {
      int row = tid >> 3, c8 = (tid & 7) * 8;
      *(u16x8*)(qg + (size_t)(row0 + row) * NH + c8) = *(const u16x8*)&qs[row][c8];
      *(u16x8*)(kg + (size_t)(row0 + row) * NH + c8) = *(const u16x8*)&ks_[row][c8];
    }
    {
      int h = tid >> 2, tc = (tid & 3) * 8;
      u16x8 vv = *(const u16x8*)&vt[h][tc];
      *(u16x8*)(vtg + ((size_t)b * NH + h) * NT + t0 + tc) = vv;
    }
  }
}

// ---------------- kernel 2: causal flash — wave-private LDS staging.
// 512 blocks = 8 b x 64 q32-tiles (heavy/light interleaved); 4 waves by
// kv-parity, kt += 4. Per step: coalesced glds16 K/V into wave-private LDS
// (XOR-swizzled via pre-swizzled source), ds_read_b128 frags, prefetch next
// tile under compute. No in-loop barriers. om merge aliases dead staging.
__global__ __launch_bounds__(256, 2) void flash(const u16* __restrict__ qg,
                                                const u16* __restrict__ kg,
                                                const u16* __restrict__ vtg,
                                                float* __restrict__ out) {
  __shared__ __align__(16) u16 stg[4][2][4096];     // [wave][K/V][64x64 u16]
  float* om = (float*)&stg[0][0][0];                // [4][32][68] aliased
  const int tid = threadIdx.x, w = tid >> 6, l = tid & 63;
  const int l31 = l & 31, hb = l >> 5;
  const int u = blockIdx.x;
  const int b = u & 7;
  const int g = u >> 3;
  const int t = (g & 1) ? (63 - (g >> 1)) : (g >> 1);
  const int nkt = (t + 2) >> 1;
  const int qrow = t * 32 + l31;

  bf16x8 qf[4];
  {
    const u16* qp = qg + ((size_t)b * NT + qrow) * NH;
#pragma unroll
    for (int ks = 0; ks < 4; ++ks) qf[ks] = ldsv8(qp + ks * 16 + hb * 8);
  }
  f32x16 o0, o1;
#pragma unroll
  for (int r = 0; r < 16; ++r) { o0[r] = 0.f; o1[r] = 0.f; }
  float lsum = 0.f;
  const char* kbase = (const char*)(kg + (size_t)b * NT * NH);   // row stride 128B
  const char* vbase = (const char*)(vtg + (size_t)b * NH * NT);  // row stride 4096B
  char* kst = (char*)&stg[w][0][0];
  char* vst = (char*)&stg[w][1][0];

  // stage kv64 tile kt into wave-private LDS; source pre-swizzled:
  // LDS[row*128 + c] = src[row][c ^ ((row&7)<<4)], dest = base + j*1024 + l*16
#define STAGE(kt_)                                                            \
  {                                                                           \
    const int kvb_ = (kt_) * 64;                                              \
    int r8 = l >> 3;                                                          \
    int inner = (l & 7) * 16;                                                 \
    int src = inner ^ (r8 << 4);                                              \
    _Pragma("unroll")                                                         \
    for (int j = 0; j < 8; ++j) {                                             \
      int row = j * 8 + r8;                                                   \
      glds16(kbase + (size_t)(kvb_ + row) * 128 + src, kst + j * 1024);       \
      glds16(vbase + (size_t)row * 4096 + kvb_ * 2 + src, vst + j * 1024);    \
    }                                                                         \
  }

  if (w < nkt) STAGE(w);

#pragma unroll 1
  for (int kt = w; kt < nkt; kt += 4) {
    const int kvb = kt * 64;
    asm volatile("s_waitcnt vmcnt(0)" ::: "memory");  // staged tile visible
    __builtin_amdgcn_sched_barrier(0);
    // ---- frags from swizzled LDS ----
    const int key = (l31 & 7) << 4;
    bf16x8 kf[4][2];
#pragma unroll
    for (int ks = 0; ks < 4; ++ks)
#pragma unroll
      for (int half = 0; half < 2; ++half) {
        int row = half * 32 + l31;
        int col = ks * 32 + hb * 16;
        kf[ks][half] = ldsv8((const u16*)(kst + row * 128 + (col ^ key)));
      }
    bf16x8 vf[2][2][2];
#pragma unroll
    for (int ht = 0; ht < 2; ++ht)
#pragma unroll
      for (int kvt = 0; kvt < 2; ++kvt)
#pragma unroll
        for (int ks2 = 0; ks2 < 2; ++ks2) {
          int row = ht * 32 + l31;
          int col = kvt * 64 + ks2 * 32 + hb * 16;
          vf[ht][kvt][ks2] = ldsv8((const u16*)(vst + row * 128 + (col ^ key)));
        }
    asm volatile("s_waitcnt lgkmcnt(0)" ::: "memory");  // frags in regs, buffer free
    __builtin_amdgcn_sched_barrier(0);
    if (kt + 4 < nkt) STAGE(kt + 4);                    // prefetch under compute

    const bool diag = (kvb + 63 > t * 32);
#pragma unroll
    for (int kvt = 0; kvt < 2; ++kvt) {
      f32x16 s;
#pragma unroll
      for (int r = 0; r < 16; ++r) s[r] = 0.f;
      __builtin_amdgcn_s_setprio(1);
#pragma unroll
      for (int ks = 0; ks < 4; ++ks)
        s = __builtin_amdgcn_mfma_f32_32x32x16_bf16(kf[ks][kvt], qf[ks], s, 0, 0, 0);
      __builtin_amdgcn_s_setprio(0);
      if (diag) {
#pragma unroll
        for (int r = 0; r < 16; ++r) {
          int kv0 = kvb + kvt * 32 + (r & 3) + 8 * (r >> 2) + 4 * hb;
          if (kv0 > qrow) s[r] = -1e30f;
        }
      }
      float p[16];
#pragma unroll
      for (int r = 0; r < 16; ++r) {
        p[r] = exp2f(fmaf(s[r], L2E, MBIAS));
        lsum += p[r];
      }
      u32 pf[2][4];
#pragma unroll
      for (int ks2 = 0; ks2 < 2; ++ks2) {
        u32 a0 = pk2(p[8 * ks2 + 0], p[8 * ks2 + 1]);
        u32 a1 = pk2(p[8 * ks2 + 2], p[8 * ks2 + 3]);
        u32 b0 = pk2(p[8 * ks2 + 4], p[8 * ks2 + 5]);
        u32 b1 = pk2(p[8 * ks2 + 6], p[8 * ks2 + 7]);
        u32 e0 = hb ? a0 : b0, e1 = hb ? a1 : b1;
        e0 = __shfl_xor(e0, 32);
        e1 = __shfl_xor(e1, 32);
        pf[ks2][0] = hb ? e0 : a0;
        pf[ks2][1] = hb ? e1 : a1;
        pf[ks2][2] = hb ? b0 : e0;
        pf[ks2][3] = hb ? b1 : e1;
      }
      __builtin_amdgcn_s_setprio(1);
#pragma unroll
      for (int ht = 0; ht < 2; ++ht)
#pragma unroll
        for (int ks2 = 0; ks2 < 2; ++ks2) {
          u32x4 pw = {pf[ks2][0], pf[ks2][1], pf[ks2][2], pf[ks2][3]};
          bf16x8 pv = __builtin_bit_cast(bf16x8, pw);
          if (ht == 0) o0 = __builtin_amdgcn_mfma_f32_32x32x16_bf16(vf[0][kvt][ks2], pv, o0, 0, 0, 0);
          else         o1 = __builtin_amdgcn_mfma_f32_32x32x16_bf16(vf[1][kvt][ks2], pv, o1, 0, 0, 0);
        }
      __builtin_amdgcn_s_setprio(0);
    }
  }
#undef STAGE
  lsum += __shfl_xor(lsum, 32);

  __syncthreads();                      // all staging reads done before om reuse
  {
    float* dst = &om[w * 2176 + l31 * 68];
#pragma unroll
    for (int ht = 0; ht < 2; ++ht)
#pragma unroll
      for (int rq = 0; rq < 4; ++rq) {
        f32x4 q4;
#pragma unroll
        for (int c = 0; c < 4; ++c) q4[c] = ht ? o1[4 * rq + c] : o0[4 * rq + c];
        *(f32x4*)&dst[ht * 32 + rq * 8 + hb * 4] = q4;
      }
    if (hb == 0) dst[64] = lsum;
  }
  __syncthreads();
  {
    int row = tid >> 3, c8 = (tid & 7) * 8;
    f32x4 a0 = {0.f, 0.f, 0.f, 0.f}, a1 = {0.f, 0.f, 0.f, 0.f};
    float ls = 0.f;
#pragma unroll
    for (int ww = 0; ww < 4; ++ww) {
      const float* sp = &om[ww * 2176 + row * 68];
      a0 += *(const f32x4*)&sp[c8];
      a1 += *(const f32x4*)&sp[c8 + 4];
      ls += sp[64];
    }
    float rl = 1.f / ls;
    size_t ob = ((size_t)b * NT + t * 32 + row) * NH + c8;
    *(f32x4*)&out[ob]     = a0 * rl;
    *(f32x4*)&out[ob + 4] = a1 * rl;
  }
}

extern "C" void kernel_launch(void* const* d_in, const int* in_sizes, int n_in,
                              void* d_out, int out_size, void* d_ws, size_t ws_size,
                              hipStream_t stream) {
  const float* x  = (const float*)d_in[0];
  const float* wk = (const float*)d_in[1];
  const float* wq = (const float*)d_in[2];
  const float* wv = (const float*)d_in[3];
  float* out = (float*)d_out;

  u16* qg  = (u16*)d_ws;                 // [B*T][64] bf16
  u16* kg  = qg + NB * NT * NH;          // [B*T][64] bf16
  u16* vtg = kg + NB * NT * NH;          // [B][64][T] bf16
  u16* wb  = vtg + NB * NT * NH;         // [3][64][1024] bf16

  wconv<<<768, 256, 0, stream>>>(wk, wq, wv, wb);
  qkv_proj<<<512, 512, 0, stream>>>(x, wb, qg, kg, vtg);
  flash<<<512, 256, 0, stream>>>(qg, kg, vtg, out);
}

// Round 15
// 49.085 us; speedup vs baseline: 5.5821x; 1.0613x over previous
//
#include <hip/hip_runtime.h>
#include <hip/hip_bf16.h>

typedef short bf16x8 __attribute__((ext_vector_type(8)));
typedef float f32x4 __attribute__((ext_vector_type(4)));
typedef float f32x16 __attribute__((ext_vector_type(16)));
typedef unsigned short u16;
typedef u16 u16x8 __attribute__((ext_vector_type(8)));
typedef unsigned int u32;
typedef u32 u32x4 __attribute__((ext_vector_type(4)));

constexpr int NB = 8, NT = 2048, NC = 1024, NH = 64;
constexpr float L2E = 1.4426950408889634f;
constexpr float MBIAS = -23.083120654223414f;   // -16*log2(e): fixed softmax max

__device__ __forceinline__ u16 f2bf(float f) {
  __hip_bfloat16 h = __float2bfloat16(f);
  return __builtin_bit_cast(u16, h);
}
__device__ __forceinline__ bf16x8 ldsv8(const u16* p) {
  return __builtin_bit_cast(bf16x8, *(const u16x8*)p);
}
__device__ __forceinline__ u32 pk2(float a, float b) {
  return (u32)f2bf(a) | ((u32)f2bf(b) << 16);
}
__device__ __forceinline__ void glds16(const void* g, void* l) {
  __builtin_amdgcn_global_load_lds((const __attribute__((address_space(1))) void*)g,
                                   (__attribute__((address_space(3))) void*)l, 16, 0, 0);
}

// ---------------- kernel 0: W fp32 [C][H] -> bf16 W^T [3][H][C]; Wq scaled 0.125
__global__ __launch_bounds__(256) void wconv(const float* __restrict__ wk,
                                             const float* __restrict__ wq,
                                             const float* __restrict__ wv,
                                             u16* __restrict__ wb) {
  int idx = blockIdx.x * 256 + threadIdx.x;   // 3*64*1024
  int m = idx >> 16, rem = idx & 65535;
  int n = rem >> 10, kk = rem & 1023;
  const float* s = (m == 0) ? wq : ((m == 1) ? wk : wv);
  float f = s[kk * NH + n];
  if (m == 0) f *= 0.125f;
  wb[idx] = f2bf(f);
}

// ---------------- kernel 1: fused QKV projection (unchanged)
__global__ __launch_bounds__(512, 4) void qkv_proj(const float* __restrict__ x,
                                                   const u16* __restrict__ wb,
                                                   u16* __restrict__ qg,
                                                   u16* __restrict__ kg,
                                                   u16* __restrict__ vtg) {
  __shared__ __align__(16) float xbuf[2][32 * 64];
  __shared__ __align__(16) u16 wlds[2][192 * 64];
  __shared__ __align__(16) u16 vt[64][40];
  __shared__ __align__(16) u16 qs[32][72];
  __shared__ __align__(16) u16 ks_[32][72];
  const int tid = threadIdx.x, w = tid >> 6, l = tid & 63;
  const int lr = l & 15, lg = l >> 4;
  const int wr = w & 1, wc = w >> 1;
  const int row0 = blockIdx.x * 32;

  f32x4 acc[3];
#pragma unroll
  for (int nt = 0; nt < 3; ++nt) acc[nt] = (f32x4){0.f, 0.f, 0.f, 0.f};

#define GSTAGE(buf, kb)                                                       \
  {                                                                           \
    int row = w * 4 + (l >> 4);                                               \
    int srci = ((l & 15) * 16) ^ ((row & 7) << 4);                            \
    glds16((const char*)x + (size_t)(row0 + row) * 4096 + (kb) * 256 + srci,  \
           (char*)&xbuf[buf][0] + w * 1024);                                  \
    _Pragma("unroll")                                                         \
    for (int i = 0; i < 3; ++i) {                                             \
      int seg = w * 3 + i;                                                    \
      int wrow = seg * 8 + (l >> 3);                                          \
      int wsrc = ((l & 7) * 16) ^ ((wrow & 7) << 4);                          \
      glds16((const char*)wb + (size_t)wrow * 2048 + (kb) * 128 + wsrc,       \
             (char*)&wlds[buf][0] + seg * 1024);                              \
    }                                                                         \
  }

  GSTAGE(0, 0);
  __syncthreads();

#pragma unroll
  for (int kb = 0; kb < 16; ++kb) {
    const int cur = kb & 1;
    if (kb < 15) GSTAGE(cur ^ 1, kb + 1);
    bf16x8 af[2];
#pragma unroll
    for (int ks = 0; ks < 2; ++ks) {
      int rowl = wr * 16 + lr;
      int sz = (lr & 7) << 4;
      int c0 = ks * 128 + lg * 32;
      f32x4 v0 = *(const f32x4*)((const char*)&xbuf[cur][0] + rowl * 256 + (c0 ^ sz));
      f32x4 v1 = *(const f32x4*)((const char*)&xbuf[cur][0] + rowl * 256 + ((c0 + 16) ^ sz));
      u16x8 tt;
#pragma unroll
      for (int j = 0; j < 4; ++j) {
        tt[j]     = f2bf(v0[j]);
        tt[j + 4] = f2bf(v1[j]);
      }
      af[ks] = __builtin_bit_cast(bf16x8, tt);
    }
#pragma unroll
    for (int nt = 0; nt < 3; ++nt)
#pragma unroll
      for (int ks = 0; ks < 2; ++ks) {
        int wrow = wc * 48 + nt * 16 + lr;
        int cb = (ks * 64 + lg * 16) ^ ((lr & 7) << 4);
        bf16x8 bf_ = ldsv8((const u16*)((const char*)&wlds[cur][0] + wrow * 128 + cb));
        acc[nt] = __builtin_amdgcn_mfma_f32_16x16x32_bf16(af[ks], bf_, acc[nt], 0, 0, 0);
      }
    __syncthreads();
  }
#undef GSTAGE

#pragma unroll
  for (int nt = 0; nt < 3; ++nt)
#pragma unroll
    for (int r = 0; r < 4; ++r) {
      int g = wc * 48 + nt * 16 + lr;
      int rl = wr * 16 + lg * 4 + r;
      u16 bv = f2bf(acc[nt][r]);
      if (g < 64)       qs[rl][g] = bv;
      else if (g < 128) ks_[rl][g - 64] = bv;
      else              vt[g - 128][rl] = bv;
    }
  __syncthreads();
  if (tid < 256) {
    int b = row0 >> 11, t0 = row0 & 2047;
    {
      int row = tid >> 3, c8 = (tid & 7) * 8;
      *(u16x8*)(qg + (size_t)(row0 + row) * NH + c8) = *(const u16x8*)&qs[row][c8];
      *(u16x8*)(kg + (size_t)(row0 + row) * NH + c8) = *(const u16x8*)&ks_[row][c8];
    }
    {
      int h = tid >> 2, tc = (tid & 3) * 8;
      u16x8 vv = *(const u16x8*)&vt[h][tc];
      *(u16x8*)(vtg + ((size_t)b * NH + h) * NT + t0 + tc) = vv;
    }
  }
}

// ---------------- kernel 2: causal flash — wave-private LDS staging.
// CU-pair-balanced t mapping: co-resident blocks g and g+32 get t and 63-t
// (every CU totals 33 kv-tiles). Otherwise identical to r14.
__global__ __launch_bounds__(256, 2) void flash(const u16* __restrict__ qg,
                                                const u16* __restrict__ kg,
                                                const u16* __restrict__ vtg,
                                                float* __restrict__ out) {
  __shared__ __align__(16) u16 stg[4][2][4096];     // [wave][K/V][64x64 u16]
  float* om = (float*)&stg[0][0][0];                // [4][32][68] aliased
  const int tid = threadIdx.x, w = tid >> 6, l = tid & 63;
  const int l31 = l & 31, hb = l >> 5;
  const int u = blockIdx.x;
  const int b = u & 7;
  const int g = u >> 3;
  const int t = (g < 32) ? g : (95 - g);            // pair (g, g+32) -> t, 63-t
  const int nkt = (t + 2) >> 1;
  const int qrow = t * 32 + l31;

  bf16x8 qf[4];
  {
    const u16* qp = qg + ((size_t)b * NT + qrow) * NH;
#pragma unroll
    for (int ks = 0; ks < 4; ++ks) qf[ks] = ldsv8(qp + ks * 16 + hb * 8);
  }
  f32x16 o0, o1;
#pragma unroll
  for (int r = 0; r < 16; ++r) { o0[r] = 0.f; o1[r] = 0.f; }
  float lsum = 0.f;
  const char* kbase = (const char*)(kg + (size_t)b * NT * NH);   // row stride 128B
  const char* vbase = (const char*)(vtg + (size_t)b * NH * NT);  // row stride 4096B
  char* kst = (char*)&stg[w][0][0];
  char* vst = (char*)&stg[w][1][0];

#define STAGE(kt_)                                                            \
  {                                                                           \
    const int kvb_ = (kt_) * 64;                                              \
    int r8 = l >> 3;                                                          \
    int inner = (l & 7) * 16;                                                 \
    int src = inner ^ (r8 << 4);                                              \
    _Pragma("unroll")                                                         \
    for (int j = 0; j < 8; ++j) {                                             \
      int row = j * 8 + r8;                                                   \
      glds16(kbase + (size_t)(kvb_ + row) * 128 + src, kst + j * 1024);       \
      glds16(vbase + (size_t)row * 4096 + kvb_ * 2 + src, vst + j * 1024);    \
    }                                                                         \
  }

  if (w < nkt) STAGE(w);

#pragma unroll 1
  for (int kt = w; kt < nkt; kt += 4) {
    const int kvb = kt * 64;
    asm volatile("s_waitcnt vmcnt(0)" ::: "memory");  // staged tile visible
    __builtin_amdgcn_sched_barrier(0);
    const int key = (l31 & 7) << 4;
    bf16x8 kf[4][2];
#pragma unroll
    for (int ks = 0; ks < 4; ++ks)
#pragma unroll
      for (int half = 0; half < 2; ++half) {
        int row = half * 32 + l31;
        int col = ks * 32 + hb * 16;
        kf[ks][half] = ldsv8((const u16*)(kst + row * 128 + (col ^ key)));
      }
    bf16x8 vf[2][2][2];
#pragma unroll
    for (int ht = 0; ht < 2; ++ht)
#pragma unroll
      for (int kvt = 0; kvt < 2; ++kvt)
#pragma unroll
        for (int ks2 = 0; ks2 < 2; ++ks2) {
          int row = ht * 32 + l31;
          int col = kvt * 64 + ks2 * 32 + hb * 16;
          vf[ht][kvt][ks2] = ldsv8((const u16*)(vst + row * 128 + (col ^ key)));
        }
    asm volatile("s_waitcnt lgkmcnt(0)" ::: "memory");  // frags in regs, buffer free
    __builtin_amdgcn_sched_barrier(0);
    if (kt + 4 < nkt) STAGE(kt + 4);                    // prefetch under compute

    const bool diag = (kvb + 63 > t * 32);
#pragma unroll
    for (int kvt = 0; kvt < 2; ++kvt) {
      f32x16 s;
#pragma unroll
      for (int r = 0; r < 16; ++r) s[r] = 0.f;
      __builtin_amdgcn_s_setprio(1);
#pragma unroll
      for (int ks = 0; ks < 4; ++ks)
        s = __builtin_amdgcn_mfma_f32_32x32x16_bf16(kf[ks][kvt], qf[ks], s, 0, 0, 0);
      __builtin_amdgcn_s_setprio(0);
      if (diag) {
#pragma unroll
        for (int r = 0; r < 16; ++r) {
          int kv0 = kvb + kvt * 32 + (r & 3) + 8 * (r >> 2) + 4 * hb;
          if (kv0 > qrow) s[r] = -1e30f;
        }
      }
      float p[16];
#pragma unroll
      for (int r = 0; r < 16; ++r) {
        p[r] = exp2f(fmaf(s[r], L2E, MBIAS));
        lsum += p[r];
      }
      u32 pf[2][4];
#pragma unroll
      for (int ks2 = 0; ks2 < 2; ++ks2) {
        u32 a0 = pk2(p[8 * ks2 + 0], p[8 * ks2 + 1]);
        u32 a1 = pk2(p[8 * ks2 + 2], p[8 * ks2 + 3]);
        u32 b0 = pk2(p[8 * ks2 + 4], p[8 * ks2 + 5]);
        u32 b1 = pk2(p[8 * ks2 + 6], p[8 * ks2 + 7]);
        u32 e0 = hb ? a0 : b0, e1 = hb ? a1 : b1;
        e0 = __shfl_xor(e0, 32);
        e1 = __shfl_xor(e1, 32);
        pf[ks2][0] = hb ? e0 : a0;
        pf[ks2][1] = hb ? e1 : a1;
        pf[ks2][2] = hb ? b0 : e0;
        pf[ks2][3] = hb ? b1 : e1;
      }
      __builtin_amdgcn_s_setprio(1);
#pragma unroll
      for (int ht = 0; ht < 2; ++ht)
#pragma unroll
        for (int ks2 = 0; ks2 < 2; ++ks2) {
          u32x4 pw = {pf[ks2][0], pf[ks2][1], pf[ks2][2], pf[ks2][3]};
          bf16x8 pv = __builtin_bit_cast(bf16x8, pw);
          if (ht == 0) o0 = __builtin_amdgcn_mfma_f32_32x32x16_bf16(vf[0][kvt][ks2], pv, o0, 0, 0, 0);
          else         o1 = __builtin_amdgcn_mfma_f32_32x32x16_bf16(vf[1][kvt][ks2], pv, o1, 0, 0, 0);
        }
      __builtin_amdgcn_s_setprio(0);
    }
  }
#undef STAGE
  lsum += __shfl_xor(lsum, 32);

  __syncthreads();                      // all staging reads done before om reuse
  {
    float* dst = &om[w * 2176 + l31 * 68];
#pragma unroll
    for (int ht = 0; ht < 2; ++ht)
#pragma unroll
      for (int rq = 0; rq < 4; ++rq) {
        f32x4 q4;
#pragma unroll
        for (int c = 0; c < 4; ++c) q4[c] = ht ? o1[4 * rq + c] : o0[4 * rq + c];
        *(f32x4*)&dst[ht * 32 + rq * 8 + hb * 4] = q4;
      }
    if (hb == 0) dst[64] = lsum;
  }
  __syncthreads();
  {
    int row = tid >> 3, c8 = (tid & 7) * 8;
    f32x4 a0 = {0.f, 0.f, 0.f, 0.f}, a1 = {0.f, 0.f, 0.f, 0.f};
    float ls = 0.f;
#pragma unroll
    for (int ww = 0; ww < 4; ++ww) {
      const float* sp = &om[ww * 2176 + row * 68];
      a0 += *(const f32x4*)&sp[c8];
      a1 += *(const f32x4*)&sp[c8 + 4];
      ls += sp[64];
    }
    float rl = 1.f / ls;
    size_t ob = ((size_t)b * NT + t * 32 + row) * NH + c8;
    *(f32x4*)&out[ob]     = a0 * rl;
    *(f32x4*)&out[ob + 4] = a1 * rl;
  }
}

extern "C" void kernel_launch(void* const* d_in, const int* in_sizes, int n_in,
                              void* d_out, int out_size, void* d_ws, size_t ws_size,
                              hipStream_t stream) {
  const float* x  = (const float*)d_in[0];
  const float* wk = (const float*)d_in[1];
  const float* wq = (const float*)d_in[2];
  const float* wv = (const float*)d_in[3];
  float* out = (float*)d_out;

  u16* qg  = (u16*)d_ws;                 // [B*T][64] bf16
  u16* kg  = qg + NB * NT * NH;          // [B*T][64] bf16
  u16* vtg = kg + NB * NT * NH;          // [B][64][T] bf16
  u16* wb  = vtg + NB * NT * NH;         // [3][64][1024] bf16

  wconv<<<768, 256, 0, stream>>>(wk, wq, wv, wb);
  qkv_proj<<<512, 512, 0, stream>>>(x, wb, qg, kg, vtg);
  flash<<<512, 256, 0, stream>>>(qg, kg, vtg, out);
}

// Round 16
// 43.406 us; speedup vs baseline: 6.3123x; 1.1308x over previous
//
#include <hip/hip_runtime.h>
#include <hip/hip_bf16.h>

typedef short bf16x8 __attribute__((ext_vector_type(8)));
typedef float f32x4 __attribute__((ext_vector_type(4)));
typedef float f32x16 __attribute__((ext_vector_type(16)));
typedef unsigned short u16;
typedef u16 u16x8 __attribute__((ext_vector_type(8)));
typedef unsigned int u32;
typedef u32 u32x4 __attribute__((ext_vector_type(4)));

constexpr int NB = 8, NT = 2048, NC = 1024, NH = 64;
constexpr float L2E = 1.4426950408889634f;
constexpr float MBIAS = -23.083120654223414f;   // -16*log2(e): fixed softmax max

__device__ __forceinline__ u16 f2bf(float f) {
  __hip_bfloat16 h = __float2bfloat16(f);
  return __builtin_bit_cast(u16, h);
}
__device__ __forceinline__ bf16x8 ldsv8(const u16* p) {
  return __builtin_bit_cast(bf16x8, *(const u16x8*)p);
}
__device__ __forceinline__ u32 pk2(float a, float b) {
  return (u32)f2bf(a) | ((u32)f2bf(b) << 16);
}
__device__ __forceinline__ void glds16(const void* g, void* l) {
  __builtin_amdgcn_global_load_lds((const __attribute__((address_space(1))) void*)g,
                                   (__attribute__((address_space(3))) void*)l, 16, 0, 0);
}

// ---------------- kernel 0: W fp32 [C][H] -> bf16 W^T [3][H][C]; Wq scaled 0.125
__global__ __launch_bounds__(256) void wconv(const float* __restrict__ wk,
                                             const float* __restrict__ wq,
                                             const float* __restrict__ wv,
                                             u16* __restrict__ wb) {
  int idx = blockIdx.x * 256 + threadIdx.x;   // 3*64*1024
  int m = idx >> 16, rem = idx & 65535;
  int n = rem >> 10, kk = rem & 1023;
  const float* s = (m == 0) ? wq : ((m == 1) ? wk : wv);
  float f = s[kk * NH + n];
  if (m == 0) f *= 0.125f;
  wb[idx] = f2bf(f);
}

// ---------------- kernel 1: fused QKV projection — 2-deep pipelined staging.
// Per iter: vmcnt(4)+barrier (buffer kb ready, kb+1 in flight) -> hoisted
// frag reads -> lgkmcnt(0)+barrier (reads done) -> GSTAGE(kb+2) into freed
// buffer -> MFMAs overlap prefetch. 4 VMEM ops/wave/stage.
__global__ __launch_bounds__(512, 4) void qkv_proj(const float* __restrict__ x,
                                                   const u16* __restrict__ wb,
                                                   u16* __restrict__ qg,
                                                   u16* __restrict__ kg,
                                                   u16* __restrict__ vtg) {
  __shared__ __align__(16) float xbuf[2][32 * 64];
  __shared__ __align__(16) u16 wlds[2][192 * 64];
  __shared__ __align__(16) u16 vt[64][40];
  __shared__ __align__(16) u16 qs[32][72];
  __shared__ __align__(16) u16 ks_[32][72];
  const int tid = threadIdx.x, w = tid >> 6, l = tid & 63;
  const int lr = l & 15, lg = l >> 4;
  const int wr = w & 1, wc = w >> 1;
  const int row0 = blockIdx.x * 32;

  f32x4 acc[3];
#pragma unroll
  for (int nt = 0; nt < 3; ++nt) acc[nt] = (f32x4){0.f, 0.f, 0.f, 0.f};

#define GSTAGE(buf, kb)                                                       \
  {                                                                           \
    int row = w * 4 + (l >> 4);                                               \
    int srci = ((l & 15) * 16) ^ ((row & 7) << 4);                            \
    glds16((const char*)x + (size_t)(row0 + row) * 4096 + (kb) * 256 + srci,  \
           (char*)&xbuf[buf][0] + w * 1024);                                  \
    _Pragma("unroll")                                                         \
    for (int i = 0; i < 3; ++i) {                                             \
      int seg = w * 3 + i;                                                    \
      int wrow = seg * 8 + (l >> 3);                                          \
      int wsrc = ((l & 7) * 16) ^ ((wrow & 7) << 4);                          \
      glds16((const char*)wb + (size_t)wrow * 2048 + (kb) * 128 + wsrc,       \
             (char*)&wlds[buf][0] + seg * 1024);                              \
    }                                                                         \
  }

  GSTAGE(0, 0);
  GSTAGE(1, 1);

#pragma unroll
  for (int kb = 0; kb < 16; ++kb) {
    const int cur = kb & 1;
    // ---- gate 1: buffer(kb) complete (its 4 loads drained; next-stage flies)
    if (kb < 15) {
      asm volatile("s_waitcnt vmcnt(4)" ::: "memory");
    } else {
      asm volatile("s_waitcnt vmcnt(0)" ::: "memory");
    }
    __builtin_amdgcn_sched_barrier(0);
    __builtin_amdgcn_s_barrier();
    // ---- hoisted frag reads (x fp32 + all 6 W B-frags) ----
    f32x4 xv[2][2];
#pragma unroll
    for (int ks = 0; ks < 2; ++ks) {
      int rowl = wr * 16 + lr;
      int sz = (lr & 7) << 4;
      int c0 = ks * 128 + lg * 32;
      xv[ks][0] = *(const f32x4*)((const char*)&xbuf[cur][0] + rowl * 256 + (c0 ^ sz));
      xv[ks][1] = *(const f32x4*)((const char*)&xbuf[cur][0] + rowl * 256 + ((c0 + 16) ^ sz));
    }
    bf16x8 bfr[3][2];
#pragma unroll
    for (int nt = 0; nt < 3; ++nt)
#pragma unroll
      for (int ks = 0; ks < 2; ++ks) {
        int wrow = wc * 48 + nt * 16 + lr;
        int cb = (ks * 64 + lg * 16) ^ ((lr & 7) << 4);
        bfr[nt][ks] = ldsv8((const u16*)((const char*)&wlds[cur][0] + wrow * 128 + cb));
      }
    // ---- gate 2: all waves finished reading buffer(kb) ----
    asm volatile("s_waitcnt lgkmcnt(0)" ::: "memory");
    __builtin_amdgcn_sched_barrier(0);
    __builtin_amdgcn_s_barrier();
    if (kb < 14) GSTAGE(cur, kb + 2);     // overwrite freed buffer(kb)
    // ---- convert + MFMA (overlaps prefetch flight) ----
    bf16x8 af[2];
#pragma unroll
    for (int ks = 0; ks < 2; ++ks) {
      u16x8 tt;
#pragma unroll
      for (int j = 0; j < 4; ++j) {
        tt[j]     = f2bf(xv[ks][0][j]);
        tt[j + 4] = f2bf(xv[ks][1][j]);
      }
      af[ks] = __builtin_bit_cast(bf16x8, tt);
    }
#pragma unroll
    for (int nt = 0; nt < 3; ++nt)
#pragma unroll
      for (int ks = 0; ks < 2; ++ks)
        acc[nt] = __builtin_amdgcn_mfma_f32_16x16x32_bf16(af[ks], bfr[nt][ks], acc[nt], 0, 0, 0);
  }
#undef GSTAGE

  // epilogue: stage q,k,v in LDS, then coalesced vec8 stores
#pragma unroll
  for (int nt = 0; nt < 3; ++nt)
#pragma unroll
    for (int r = 0; r < 4; ++r) {
      int g = wc * 48 + nt * 16 + lr;
      int rl = wr * 16 + lg * 4 + r;
      u16 bv = f2bf(acc[nt][r]);
      if (g < 64)       qs[rl][g] = bv;
      else if (g < 128) ks_[rl][g - 64] = bv;
      else              vt[g - 128][rl] = bv;
    }
  __syncthreads();
  if (tid < 256) {
    int b = row0 >> 11, t0 = row0 & 2047;
    {
      int row = tid >> 3, c8 = (tid & 7) * 8;
      *(u16x8*)(qg + (size_t)(row0 + row) * NH + c8) = *(const u16x8*)&qs[row][c8];
      *(u16x8*)(kg + (size_t)(row0 + row) * NH + c8) = *(const u16x8*)&ks_[row][c8];
    }
    {
      int h = tid >> 2, tc = (tid & 3) * 8;
      u16x8 vv = *(const u16x8*)&vt[h][tc];
      *(u16x8*)(vtg + ((size_t)b * NH + h) * NT + t0 + tc) = vv;
    }
  }
}

// ---------------- kernel 2: causal flash — wave-private LDS staging (r15).
__global__ __launch_bounds__(256, 2) void flash(const u16* __restrict__ qg,
                                                const u16* __restrict__ kg,
                                                const u16* __restrict__ vtg,
                                                float* __restrict__ out) {
  __shared__ __align__(16) u16 stg[4][2][4096];     // [wave][K/V][64x64 u16]
  float* om = (float*)&stg[0][0][0];                // [4][32][68] aliased
  const int tid = threadIdx.x, w = tid >> 6, l = tid & 63;
  const int l31 = l & 31, hb = l >> 5;
  const int u = blockIdx.x;
  const int b = u & 7;
  const int g = u >> 3;
  const int t = (g < 32) ? g : (95 - g);            // pair (g, g+32) -> t, 63-t
  const int nkt = (t + 2) >> 1;
  const int qrow = t * 32 + l31;

  bf16x8 qf[4];
  {
    const u16* qp = qg + ((size_t)b * NT + qrow) * NH;
#pragma unroll
    for (int ks = 0; ks < 4; ++ks) qf[ks] = ldsv8(qp + ks * 16 + hb * 8);
  }
  f32x16 o0, o1;
#pragma unroll
  for (int r = 0; r < 16; ++r) { o0[r] = 0.f; o1[r] = 0.f; }
  float lsum = 0.f;
  const char* kbase = (const char*)(kg + (size_t)b * NT * NH);   // row stride 128B
  const char* vbase = (const char*)(vtg + (size_t)b * NH * NT);  // row stride 4096B
  char* kst = (char*)&stg[w][0][0];
  char* vst = (char*)&stg[w][1][0];

#define STAGE(kt_)                                                            \
  {                                                                           \
    const int kvb_ = (kt_) * 64;                                              \
    int r8 = l >> 3;                                                          \
    int inner = (l & 7) * 16;                                                 \
    int src = inner ^ (r8 << 4);                                              \
    _Pragma("unroll")                                                         \
    for (int j = 0; j < 8; ++j) {                                             \
      int row = j * 8 + r8;                                                   \
      glds16(kbase + (size_t)(kvb_ + row) * 128 + src, kst + j * 1024);       \
      glds16(vbase + (size_t)row * 4096 + kvb_ * 2 + src, vst + j * 1024);    \
    }                                                                         \
  }

  if (w < nkt) STAGE(w);

#pragma unroll 1
  for (int kt = w; kt < nkt; kt += 4) {
    const int kvb = kt * 64;
    asm volatile("s_waitcnt vmcnt(0)" ::: "memory");  // staged tile visible
    __builtin_amdgcn_sched_barrier(0);
    const int key = (l31 & 7) << 4;
    bf16x8 kf[4][2];
#pragma unroll
    for (int ks = 0; ks < 4; ++ks)
#pragma unroll
      for (int half = 0; half < 2; ++half) {
        int row = half * 32 + l31;
        int col = ks * 32 + hb * 16;
        kf[ks][half] = ldsv8((const u16*)(kst + row * 128 + (col ^ key)));
      }
    bf16x8 vf[2][2][2];
#pragma unroll
    for (int ht = 0; ht < 2; ++ht)
#pragma unroll
      for (int kvt = 0; kvt < 2; ++kvt)
#pragma unroll
        for (int ks2 = 0; ks2 < 2; ++ks2) {
          int row = ht * 32 + l31;
          int col = kvt * 64 + ks2 * 32 + hb * 16;
          vf[ht][kvt][ks2] = ldsv8((const u16*)(vst + row * 128 + (col ^ key)));
        }
    asm volatile("s_waitcnt lgkmcnt(0)" ::: "memory");  // frags in regs, buffer free
    __builtin_amdgcn_sched_barrier(0);
    if (kt + 4 < nkt) STAGE(kt + 4);                    // prefetch under compute

    const bool diag = (kvb + 63 > t * 32);
#pragma unroll
    for (int kvt = 0; kvt < 2; ++kvt) {
      f32x16 s;
#pragma unroll
      for (int r = 0; r < 16; ++r) s[r] = 0.f;
      __builtin_amdgcn_s_setprio(1);
#pragma unroll
      for (int ks = 0; ks < 4; ++ks)
        s = __builtin_amdgcn_mfma_f32_32x32x16_bf16(kf[ks][kvt], qf[ks], s, 0, 0, 0);
      __builtin_amdgcn_s_setprio(0);
      if (diag) {
#pragma unroll
        for (int r = 0; r < 16; ++r) {
          int kv0 = kvb + kvt * 32 + (r & 3) + 8 * (r >> 2) + 4 * hb;
          if (kv0 > qrow) s[r] = -1e30f;
        }
      }
      float p[16];
#pragma unroll
      for (int r = 0; r < 16; ++r) {
        p[r] = exp2f(fmaf(s[r], L2E, MBIAS));
        lsum += p[r];
      }
      u32 pf[2][4];
#pragma unroll
      for (int ks2 = 0; ks2 < 2; ++ks2) {
        u32 a0 = pk2(p[8 * ks2 + 0], p[8 * ks2 + 1]);
        u32 a1 = pk2(p[8 * ks2 + 2], p[8 * ks2 + 3]);
        u32 b0 = pk2(p[8 * ks2 + 4], p[8 * ks2 + 5]);
        u32 b1 = pk2(p[8 * ks2 + 6], p[8 * ks2 + 7]);
        u32 e0 = hb ? a0 : b0, e1 = hb ? a1 : b1;
        e0 = __shfl_xor(e0, 32);
        e1 = __shfl_xor(e1, 32);
        pf[ks2][0] = hb ? e0 : a0;
        pf[ks2][1] = hb ? e1 : a1;
        pf[ks2][2] = hb ? b0 : e0;
        pf[ks2][3] = hb ? b1 : e1;
      }
      __builtin_amdgcn_s_setprio(1);
#pragma unroll
      for (int ht = 0; ht < 2; ++ht)
#pragma unroll
        for (int ks2 = 0; ks2 < 2; ++ks2) {
          u32x4 pw = {pf[ks2][0], pf[ks2][1], pf[ks2][2], pf[ks2][3]};
          bf16x8 pv = __builtin_bit_cast(bf16x8, pw);
          if (ht == 0) o0 = __builtin_amdgcn_mfma_f32_32x32x16_bf16(vf[0][kvt][ks2], pv, o0, 0, 0, 0);
          else         o1 = __builtin_amdgcn_mfma_f32_32x32x16_bf16(vf[1][kvt][ks2], pv, o1, 0, 0, 0);
        }
      __builtin_amdgcn_s_setprio(0);
    }
  }
#undef STAGE
  lsum += __shfl_xor(lsum, 32);

  __syncthreads();                      // all staging reads done before om reuse
  {
    float* dst = &om[w * 2176 + l31 * 68];
#pragma unroll
    for (int ht = 0; ht < 2; ++ht)
#pragma unroll
      for (int rq = 0; rq < 4; ++rq) {
        f32x4 q4;
#pragma unroll
        for (int c = 0; c < 4; ++c) q4[c] = ht ? o1[4 * rq + c] : o0[4 * rq + c];
        *(f32x4*)&dst[ht * 32 + rq * 8 + hb * 4] = q4;
      }
    if (hb == 0) dst[64] = lsum;
  }
  __syncthreads();
  {
    int row = tid >> 3, c8 = (tid & 7) * 8;
    f32x4 a0 = {0.f, 0.f, 0.f, 0.f}, a1 = {0.f, 0.f, 0.f, 0.f};
    float ls = 0.f;
#pragma unroll
    for (int ww = 0; ww < 4; ++ww) {
      const float* sp = &om[ww * 2176 + row * 68];
      a0 += *(const f32x4*)&sp[c8];
      a1 += *(const f32x4*)&sp[c8 + 4];
      ls += sp[64];
    }
    float rl = 1.f / ls;
    size_t ob = ((size_t)b * NT + t * 32 + row) * NH + c8;
    *(f32x4*)&out[ob]     = a0 * rl;
    *(f32x4*)&out[ob + 4] = a1 * rl;
  }
}

extern "C" void kernel_launch(void* const* d_in, const int* in_sizes, int n_in,
                              void* d_out, int out_size, void* d_ws, size_t ws_size,
                              hipStream_t stream) {
  const float* x  = (const float*)d_in[0];
  const float* wk = (const float*)d_in[1];
  const float* wq = (const float*)d_in[2];
  const float* wv = (const float*)d_in[3];
  float* out = (float*)d_out;

  u16* qg  = (u16*)d_ws;                 // [B*T][64] bf16
  u16* kg  = qg + NB * NT * NH;          // [B*T][64] bf16
  u16* vtg = kg + NB * NT * NH;          // [B][64][T] bf16
  u16* wb  = vtg + NB * NT * NH;         // [3][64][1024] bf16

  wconv<<<768, 256, 0, stream>>>(wk, wq, wv, wb);
  qkv_proj<<<512, 512, 0, stream>>>(x, wb, qg, kg, vtg);
  flash<<<512, 256, 0, stream>>>(qg, kg, vtg, out);
}